// Round 1
// baseline (5999.287 us; speedup 1.0000x reference)
//
#include <hip/hip_runtime.h>
#include <math.h>

#define BATCH 16
#define NPTS  2048
#define DIM   768

// ---------------- normalize: fn = f / max(||f||,1e-12), fp64 norm ----------------
__global__ void normalize_k(const float* __restrict__ feat, float* __restrict__ fn, int cs) {
  const int rn = blockIdx.x;                 // ci*NPTS + n
  const int ci = rn >> 11, n = rn & (NPTS - 1);
  const float* src = feat + ((size_t)(cs + ci) * NPTS + n) * DIM;
  const int t = threadIdx.x;                 // 256 threads
  float f0 = src[t], f1 = src[t + 256], f2 = src[t + 512];
  double s = (double)f0 * (double)f0 + (double)f1 * (double)f1 + (double)f2 * (double)f2;
  for (int off = 32; off > 0; off >>= 1) s += __shfl_down(s, off);
  __shared__ double ps[4];
  __shared__ double rbc;
  const int lane = t & 63, wid = t >> 6;
  if (lane == 0) ps[wid] = s;
  __syncthreads();
  if (t == 0) {
    double tot = ps[0] + ps[1] + ps[2] + ps[3];
    rbc = fmax(sqrt(tot), 1e-12);
  }
  __syncthreads();
  const double r = rbc;
  float* dst = fn + ((size_t)ci * NPTS + n) * DIM;
  dst[t]       = (float)((double)f0 / r);
  dst[t + 256] = (float)((double)f1 / r);
  dst[t + 512] = (float)((double)f2 / r);
}

// ---------------- similarity: S = fn.fn^T (fp64 acc) + 0.5*exp(-d2/1e4) ----------------
// 128x128 tile per block (16x16 threads, 8x8 fp64 micro-tile), k-chunk 16.
__global__ __launch_bounds__(256, 2) void gemm_k(const float* __restrict__ fn,
                                                 const float* __restrict__ coords,
                                                 float* __restrict__ S, int cs) {
  const int ci = blockIdx.z;
  const int i0 = blockIdx.x * 128;
  const int j0 = blockIdx.y * 128;
  const int tx = threadIdx.x, ty = threadIdx.y;
  const int tid = ty * 16 + tx;
  __shared__ double Ad[16][130];   // [k][i], k-major: B-reads conflict-free, A-reads broadcast
  __shared__ double Bd[16][130];
  double acc[8][8];
#pragma unroll
  for (int r = 0; r < 8; ++r)
#pragma unroll
    for (int c = 0; c < 8; ++c) acc[r][c] = 0.0;

  const float* fb = fn + (size_t)ci * NPTS * DIM;
  const int row = tid >> 1;      // 0..127
  const int half = tid & 1;      // which 8-wide k slice

  for (int k0 = 0; k0 < DIM; k0 += 16) {
    __syncthreads();
    {
      const float* sa = fb + (size_t)(i0 + row) * DIM + k0 + half * 8;
      float4 a0 = *(const float4*)sa;
      float4 a1 = *(const float4*)(sa + 4);
      const int kk = half * 8;
      Ad[kk + 0][row] = a0.x; Ad[kk + 1][row] = a0.y; Ad[kk + 2][row] = a0.z; Ad[kk + 3][row] = a0.w;
      Ad[kk + 4][row] = a1.x; Ad[kk + 5][row] = a1.y; Ad[kk + 6][row] = a1.z; Ad[kk + 7][row] = a1.w;
      const float* sb = fb + (size_t)(j0 + row) * DIM + k0 + half * 8;
      float4 b0 = *(const float4*)sb;
      float4 b1 = *(const float4*)(sb + 4);
      Bd[kk + 0][row] = b0.x; Bd[kk + 1][row] = b0.y; Bd[kk + 2][row] = b0.z; Bd[kk + 3][row] = b0.w;
      Bd[kk + 4][row] = b1.x; Bd[kk + 5][row] = b1.y; Bd[kk + 6][row] = b1.z; Bd[kk + 7][row] = b1.w;
    }
    __syncthreads();
#pragma unroll
    for (int k = 0; k < 16; ++k) {
      double a[8], b[8];
      const double* ap = &Ad[k][8 * ty];
#pragma unroll
      for (int r = 0; r < 8; r += 2) { double2 v = *(const double2*)(ap + r); a[r] = v.x; a[r + 1] = v.y; }
#pragma unroll
      for (int c = 0; c < 8; ++c) b[c] = Bd[k][tx + 16 * c];
#pragma unroll
      for (int r = 0; r < 8; ++r)
#pragma unroll
        for (int c = 0; c < 8; ++c) acc[r][c] = fma(a[r], b[c], acc[r][c]);
    }
  }

  // epilogue: + 0.5 * exp(-sq_dist/10000), exp via 4th-order Taylor (x<=2e-4, err ~1e-20)
  const float* cb = coords + (size_t)(cs + ci) * NPTS * 2;
  double cxi[8], cyi[8], cxj[8], cyj[8];
#pragma unroll
  for (int r = 0; r < 8; ++r) { float2 p = *(const float2*)(cb + 2 * (i0 + 8 * ty + r)); cxi[r] = p.x; cyi[r] = p.y; }
#pragma unroll
  for (int c = 0; c < 8; ++c) { float2 p = *(const float2*)(cb + 2 * (j0 + tx + 16 * c)); cxj[c] = p.x; cyj[c] = p.y; }
  float* Sb = S + (size_t)ci * NPTS * NPTS;
#pragma unroll
  for (int r = 0; r < 8; ++r) {
    float* orow = Sb + (size_t)(i0 + 8 * ty + r) * NPTS + j0;
#pragma unroll
    for (int c = 0; c < 8; ++c) {
      double dx = cxi[r] - cxj[c], dy = cyi[r] - cyj[c];
      double x = (dx * dx + dy * dy) * (1.0 / 10000.0);
      double e = 1.0 - x * (1.0 - x * (0.5 - x * ((1.0 / 6.0) - x * (1.0 / 24.0))));
      orow[tx + 16 * c] = (float)(acc[r][c] + 0.5 * e);
    }
  }
}

// ---------------- row sums (fp64) for start-node selection ----------------
__global__ void rowsum_k(const float* __restrict__ S, double* __restrict__ rs) {
  const size_t r = blockIdx.x;
  const float* row = S + r * NPTS;
  const int t = threadIdx.x;   // 256
  double s = 0.0;
#pragma unroll
  for (int j = 0; j < 8; ++j) s += (double)row[t + j * 256];
  for (int off = 32; off > 0; off >>= 1) s += __shfl_down(s, off);
  __shared__ double ps[4];
  if ((t & 63) == 0) ps[t >> 6] = s;
  __syncthreads();
  if (t == 0) rs[r] = ps[0] + ps[1] + ps[2] + ps[3];
}

// ---------------- greedy traversal: one block per batch ----------------
__global__ __launch_bounds__(512) void traverse_k(const float* __restrict__ S,
                                                  const double* __restrict__ rs,
                                                  float* __restrict__ order_f, int cs) {
  const int ci = blockIdx.x;
  const int gb = cs + ci;
  const int t = threadIdx.x;   // 512 threads, 8 waves
  const int lane = t & 63, wid = t >> 6;
  __shared__ __align__(16) float mask[NPTS];   // 0 = unvisited, -inf = visited
  __shared__ float wv[8];
  __shared__ int wi[8];
  __shared__ double wvd[8];
  __shared__ int bcast;
  ((float4*)mask)[t] = make_float4(0.f, 0.f, 0.f, 0.f);

  // start = argmax_i rowsum (first-index tie-break, like jnp.argmax)
  const double* rb = rs + (size_t)ci * NPTS;
  double dv = -1.0e300; int di = 0;
#pragma unroll
  for (int c = 0; c < 4; ++c) {
    int j = 4 * t + c;
    double v = rb[j];
    if (v > dv) { dv = v; di = j; }
  }
  for (int off = 32; off > 0; off >>= 1) {
    double vo = __shfl_down(dv, off);
    int io = __shfl_down(di, off);
    if (vo > dv || (vo == dv && io < di)) { dv = vo; di = io; }
  }
  if (lane == 0) { wvd[wid] = dv; wi[wid] = di; }
  __syncthreads();
  if (t == 0) {
    double bv = wvd[0]; int bi = wi[0];
    for (int w = 1; w < 8; ++w)
      if (wvd[w] > bv || (wvd[w] == bv && wi[w] < bi)) { bv = wvd[w]; bi = wi[w]; }
    order_f[(size_t)gb * NPTS] = (float)bi;
    mask[bi] = -INFINITY;
    bcast = bi;
  }
  __syncthreads();
  int cur = bcast;
  const float* Sb = S + (size_t)ci * NPTS * NPTS;

  for (int s = 1; s < NPTS; ++s) {
    const float4 sv = ((const float4*)(Sb + (size_t)cur * NPTS))[t];
    const float4 mv = ((const float4*)mask)[t];
    float v0 = sv.x + mv.x, v1 = sv.y + mv.y, v2 = sv.z + mv.z, v3 = sv.w + mv.w;
    float bv = v0; int bi = 4 * t;
    if (v1 > bv) { bv = v1; bi = 4 * t + 1; }
    if (v2 > bv) { bv = v2; bi = 4 * t + 2; }
    if (v3 > bv) { bv = v3; bi = 4 * t + 3; }
    for (int off = 32; off > 0; off >>= 1) {
      float vo = __shfl_down(bv, off);
      int io = __shfl_down(bi, off);
      if (vo > bv || (vo == bv && io < bi)) { bv = vo; bi = io; }
    }
    if (lane == 0) { wv[wid] = bv; wi[wid] = bi; }
    __syncthreads();
    if (t == 0) {
      float fbv = wv[0]; int fbi = wi[0];
      for (int w = 1; w < 8; ++w)
        if (wv[w] > fbv || (wv[w] == fbv && wi[w] < fbi)) { fbv = wv[w]; fbi = wi[w]; }
      order_f[(size_t)gb * NPTS + s] = (float)fbi;
      mask[fbi] = -INFINITY;
      bcast = fbi;
    }
    __syncthreads();
    cur = bcast;
  }
}

// ---------------- gather: reordered = features[order] ----------------
__global__ void gather_k(const float* __restrict__ feat, const float* __restrict__ order_f,
                         float* __restrict__ out) {
  const int bk = blockIdx.x;
  const int b = bk >> 11, k = bk & (NPTS - 1);
  const int idx = (int)order_f[(size_t)b * NPTS + k];
  const float4* src = (const float4*)(feat + ((size_t)b * NPTS + idx) * DIM);
  float4* dst = (float4*)(out + ((size_t)b * NPTS + k) * DIM);
  dst[threadIdx.x] = src[threadIdx.x];   // 192 threads x float4 = 768 floats
}

extern "C" void kernel_launch(void* const* d_in, const int* in_sizes, int n_in,
                              void* d_out, int out_size, void* d_ws, size_t ws_size,
                              hipStream_t stream) {
  const float* features = (const float*)d_in[0];
  const float* coords   = (const float*)d_in[1];
  float* out = (float*)d_out;
  float* order_f = out + (size_t)BATCH * NPTS * DIM;   // order stored as float values

  // ws per batch: rowsum (N*8) + S (N*N*4) + fn (N*D*4)
  const size_t per_b = (size_t)NPTS * 8 + (size_t)NPTS * NPTS * 4 + (size_t)NPTS * DIM * 4;
  int C = BATCH;
  while (C > 1 && per_b * (size_t)C > ws_size) C >>= 1;   // chunked fallback if ws is small

  char* wp = (char*)d_ws;
  double* rowsum = (double*)wp;
  float* S  = (float*)(wp + (size_t)C * NPTS * 8);
  float* fn = (float*)(wp + (size_t)C * NPTS * 8 + (size_t)C * NPTS * NPTS * 4);

  for (int cs = 0; cs < BATCH; cs += C) {
    normalize_k<<<dim3(C * NPTS), dim3(256), 0, stream>>>(features, fn, cs);
    gemm_k<<<dim3(16, 16, C), dim3(16, 16), 0, stream>>>(fn, coords, S, cs);
    rowsum_k<<<dim3(C * NPTS), dim3(256), 0, stream>>>(S, rowsum);
    traverse_k<<<dim3(C), dim3(512), 0, stream>>>(S, rowsum, order_f, cs);
  }
  gather_k<<<dim3(BATCH * NPTS), dim3(192), 0, stream>>>(features, order_f, out);
}